// Round 1
// baseline (521.855 us; speedup 1.0000x reference)
//
#include <hip/hip_runtime.h>
#include <hip/hip_bf16.h>

// Workspace layout (float offsets)
#define WS_AS   0                       // 32*128   : emb[s]@W1[0:32]  + b1
#define WS_BT   4096                    // 32*128   : emb[t]@W1[32:64]
#define WS_CE   8192                    // 256*128  : emb[u]@W1[64:96] + emb[v]@W1[96:128]
#define WS_A    40960                   // 1024*32*32 routing matrices
#define WS_RBC  (40960 + 1048576)       // 32 accumulator

__global__ __launch_bounds__(256) void precompute_kernel(
    const float* __restrict__ emb, const int* __restrict__ edges,
    const float* __restrict__ W1, const float* __restrict__ b1,
    float* __restrict__ ws)
{
  float* As = ws + WS_AS;
  float* Bt = ws + WS_BT;
  float* Ce = ws + WS_CE;
  int idx0 = blockIdx.x * blockDim.x + threadIdx.x;
  int stride = gridDim.x * blockDim.x;
  for (int i = idx0; i < 4096 + 4096 + 32768; i += stride) {
    if (i < 4096) {
      int s = i >> 7, j = i & 127;
      float acc = b1[j];
      #pragma unroll
      for (int k = 0; k < 32; ++k) acc += emb[s*32 + k] * W1[k*128 + j];
      As[i] = acc;
    } else if (i < 8192) {
      int ii = i - 4096;
      int t = ii >> 7, j = ii & 127;
      float acc = 0.f;
      #pragma unroll
      for (int k = 0; k < 32; ++k) acc += emb[t*32 + k] * W1[(32+k)*128 + j];
      Bt[ii] = acc;
    } else {
      int ii = i - 8192;
      int e = ii >> 7, j = ii & 127;
      int u = edges[2*e], v = edges[2*e + 1];
      float acc = 0.f;
      #pragma unroll
      for (int k = 0; k < 32; ++k) {
        acc += emb[u*32 + k] * W1[(64+k)*128 + j];
        acc += emb[v*32 + k] * W1[(96+k)*128 + j];
      }
      Ce[ii] = acc;
    }
  }
}

__device__ __forceinline__ float f4get(const float4& v, int i) {
  switch (i) { case 0: return v.x; case 1: return v.y; case 2: return v.z; default: return v.w; }
}

// One WG = 64 rows (one quarter of one (s,t) pair's 256 edges).
// LDS union buffer: h1[64][128] then h2[64][256] (64 KB -> 2 WG/CU).
__global__ __launch_bounds__(256, 2) void mlp_kernel(
    const int* __restrict__ edges,
    const float* __restrict__ W2, const float* __restrict__ b2,
    const float* __restrict__ W3, const float* __restrict__ b3,
    const float* __restrict__ W4, const float* __restrict__ b4,
    float* __restrict__ ws)
{
  __shared__ float sh[64 * 256];
  const float* As = ws + WS_AS;
  const float* Bt = ws + WS_BT;
  const float* Ce = ws + WS_CE;
  float* A = ws + WS_A;

  const int b  = blockIdx.x;
  const int p  = b >> 2;
  const int e0 = (b & 3) << 6;
  const int s  = p >> 5, t = p & 31;
  const int tid = threadIdx.x;

  // phase A: h1 = relu(As[s] + Bt[t] + Ce[e])  (b1 folded into As)
  for (int i = tid; i < 64 * 128; i += 256) {
    int r = i >> 7, j = i & 127;
    float h = As[s*128 + j] + Bt[t*128 + j] + Ce[(e0 + r)*128 + j];
    sh[r*128 + j] = fmaxf(h, 0.f);
  }
  __syncthreads();

  // phase B: h2 = relu(h1 @ W2 + b2); thread tile 8 rows x 8 cols
  const int rg = tid >> 5;        // 8 row groups
  const int cg = tid & 31;        // 32 col groups
  const int c2 = cg << 3;
  float acc2[8][8];
  #pragma unroll
  for (int i = 0; i < 8; ++i)
    #pragma unroll
    for (int j = 0; j < 8; ++j) acc2[i][j] = 0.f;

  for (int k = 0; k < 128; k += 4) {
    float4 a4[8];
    #pragma unroll
    for (int i = 0; i < 8; ++i)
      a4[i] = *(const float4*)&sh[(rg*8 + i)*128 + k];
    #pragma unroll
    for (int kk = 0; kk < 4; ++kk) {
      float4 w0 = *(const float4*)&W2[(k + kk)*256 + c2];
      float4 w1 = *(const float4*)&W2[(k + kk)*256 + c2 + 4];
      #pragma unroll
      for (int i = 0; i < 8; ++i) {
        float a = f4get(a4[i], kk);
        acc2[i][0] += a * w0.x;  acc2[i][1] += a * w0.y;
        acc2[i][2] += a * w0.z;  acc2[i][3] += a * w0.w;
        acc2[i][4] += a * w1.x;  acc2[i][5] += a * w1.y;
        acc2[i][6] += a * w1.z;  acc2[i][7] += a * w1.w;
      }
    }
  }
  __syncthreads();   // all h1 reads done; reuse LDS for h2

  {
    float4 b2v0 = *(const float4*)&b2[c2];
    float4 b2v1 = *(const float4*)&b2[c2 + 4];
    #pragma unroll
    for (int i = 0; i < 8; ++i) {
      float4 h0, h1v;
      h0.x  = fmaxf(acc2[i][0] + b2v0.x, 0.f);
      h0.y  = fmaxf(acc2[i][1] + b2v0.y, 0.f);
      h0.z  = fmaxf(acc2[i][2] + b2v0.z, 0.f);
      h0.w  = fmaxf(acc2[i][3] + b2v0.w, 0.f);
      h1v.x = fmaxf(acc2[i][4] + b2v1.x, 0.f);
      h1v.y = fmaxf(acc2[i][5] + b2v1.y, 0.f);
      h1v.z = fmaxf(acc2[i][6] + b2v1.z, 0.f);
      h1v.w = fmaxf(acc2[i][7] + b2v1.w, 0.f);
      *(float4*)&sh[(rg*8 + i)*256 + c2]     = h0;
      *(float4*)&sh[(rg*8 + i)*256 + c2 + 4] = h1v;
    }
  }
  __syncthreads();

  // phase C: h3 = relu(h2 @ W3 + b3); thread tile 4 rows x 8 cols
  const int rg3 = tid >> 4;       // 16 row groups of 4
  const int cg3 = tid & 15;       // 16 col groups of 8
  const int c3 = cg3 << 3;
  float acc3[4][8];
  #pragma unroll
  for (int i = 0; i < 4; ++i)
    #pragma unroll
    for (int j = 0; j < 8; ++j) acc3[i][j] = 0.f;

  for (int k = 0; k < 256; k += 4) {
    float4 a4[4];
    #pragma unroll
    for (int i = 0; i < 4; ++i)
      a4[i] = *(const float4*)&sh[(rg3*4 + i)*256 + k];
    #pragma unroll
    for (int kk = 0; kk < 4; ++kk) {
      float4 w0 = *(const float4*)&W3[(k + kk)*128 + c3];
      float4 w1 = *(const float4*)&W3[(k + kk)*128 + c3 + 4];
      #pragma unroll
      for (int i = 0; i < 4; ++i) {
        float a = f4get(a4[i], kk);
        acc3[i][0] += a * w0.x;  acc3[i][1] += a * w0.y;
        acc3[i][2] += a * w0.z;  acc3[i][3] += a * w0.w;
        acc3[i][4] += a * w1.x;  acc3[i][5] += a * w1.y;
        acc3[i][6] += a * w1.z;  acc3[i][7] += a * w1.w;
      }
    }
  }

  // phase D: pred = h3 @ W4 + b4; reduce over the 16 col groups; scatter
  float4 b3v0 = *(const float4*)&b3[c3];
  float4 b3v1 = *(const float4*)&b3[c3 + 4];
  float4 w40  = *(const float4*)&W4[c3];
  float4 w41  = *(const float4*)&W4[c3 + 4];
  float part[4];
  #pragma unroll
  for (int i = 0; i < 4; ++i) {
    float h0 = fmaxf(acc3[i][0] + b3v0.x, 0.f);
    float h1 = fmaxf(acc3[i][1] + b3v0.y, 0.f);
    float h2 = fmaxf(acc3[i][2] + b3v0.z, 0.f);
    float h3 = fmaxf(acc3[i][3] + b3v0.w, 0.f);
    float h4 = fmaxf(acc3[i][4] + b3v1.x, 0.f);
    float h5 = fmaxf(acc3[i][5] + b3v1.y, 0.f);
    float h6 = fmaxf(acc3[i][6] + b3v1.z, 0.f);
    float h7 = fmaxf(acc3[i][7] + b3v1.w, 0.f);
    part[i] = h0*w40.x + h1*w40.y + h2*w40.z + h3*w40.w
            + h4*w41.x + h5*w41.y + h6*w41.z + h7*w41.w;
  }
  #pragma unroll
  for (int off = 8; off; off >>= 1)
    #pragma unroll
    for (int i = 0; i < 4; ++i)
      part[i] += __shfl_xor(part[i], off, 16);

  if (cg3 == 0) {
    float bb4 = b4[0];
    #pragma unroll
    for (int i = 0; i < 4; ++i) {
      int e = e0 + rg3*4 + i;
      int u = edges[2*e], v = edges[2*e + 1];
      atomicAdd(&A[p*1024 + u*32 + v], part[i] + bb4);
    }
  }
}

// One 32-lane half-wave per (s,t) pair: lane v holds column v of A (32 regs).
// y_v = sum_u x_u * A[u][v] via broadcast shuffles; L2-normalize; 50 iters.
__global__ __launch_bounds__(256) void power_kernel(float* __restrict__ ws)
{
  float* A   = ws + WS_A;
  float* rbc = ws + WS_RBC;
  const int gtid = blockIdx.x * blockDim.x + threadIdx.x;
  const int lane = threadIdx.x & 63;
  const int h = lane >> 5;
  const int v = lane & 31;
  const int wave = gtid >> 6;
  const int p = wave * 2 + h;          // grid sized exactly for 1024 pairs
  const int s = p >> 5, t = p & 31;

  float Acol[32];
  #pragma unroll
  for (int u = 0; u < 32; ++u) Acol[u] = A[p*1024 + u*32 + v];
  if (v == s) Acol[s] += 1.0f;         // R[s,t,s,s] += 1

  float x = 1.0f / 32.0f;
  for (int it = 0; it < 50; ++it) {
    float y = 0.f;
    #pragma unroll
    for (int u = 0; u < 32; ++u)
      y += __shfl(x, u, 32) * Acol[u];
    float ss = y * y;
    #pragma unroll
    for (int off = 16; off; off >>= 1)
      ss += __shfl_xor(ss, off, 32);
    x = y / (sqrtf(ss) + 1e-9f);
  }
  float xs = __shfl(x, s, 32);         // component at source node
  float delta = x / (xs + 1e-9f);
  float dm = (s != t) ? delta : 0.f;
  dm += __shfl_xor(dm, 32, 64);        // combine the two pairs in this wave
  if (h == 0) atomicAdd(&rbc[v], dm);
}

__global__ void finalize_kernel(const float* __restrict__ ws, float* __restrict__ out)
{
  const float* rbc = ws + WS_RBC;
  int v = threadIdx.x;                  // 32 threads
  float val = rbc[v];
  float sum = val;
  #pragma unroll
  for (int off = 16; off; off >>= 1)
    sum += __shfl_xor(sum, off, 32);
  out[v] = val / sum;
}

extern "C" void kernel_launch(void* const* d_in, const int* in_sizes, int n_in,
                              void* d_out, int out_size, void* d_ws, size_t ws_size,
                              hipStream_t stream) {
  (void)in_sizes; (void)n_in; (void)out_size; (void)ws_size;
  const float* emb  = (const float*)d_in[1];
  const int*   edges = (const int*)d_in[2];
  const float* W1 = (const float*)d_in[3];
  const float* b1 = (const float*)d_in[4];
  const float* W2 = (const float*)d_in[5];
  const float* b2 = (const float*)d_in[6];
  const float* W3 = (const float*)d_in[7];
  const float* b3 = (const float*)d_in[8];
  const float* W4 = (const float*)d_in[9];
  const float* b4 = (const float*)d_in[10];
  float* out = (float*)d_out;
  float* ws  = (float*)d_ws;

  // zero the A matrices + rbc accumulator (ws is poisoned 0xAA each launch)
  hipMemsetAsync(ws + WS_A, 0, (1048576 + 32) * sizeof(float), stream);

  precompute_kernel<<<64, 256, 0, stream>>>(emb, edges, W1, b1, ws);
  mlp_kernel<<<4096, 256, 0, stream>>>(edges, W2, b2, W3, b3, W4, b4, ws);
  power_kernel<<<128, 256, 0, stream>>>(ws);
  finalize_kernel<<<1, 32, 0, stream>>>(ws, out);
}